// Round 6
// baseline (125.524 us; speedup 1.0000x reference)
//
#include <hip/hip_runtime.h>
#include <math.h>

#define H 256
#define OUTD 218
#define BMT 64                  // rows per tile
#define NBATCH 64
#define NPTS 4096
#define NTOT (NBATCH * NPTS)
#define NBLK 256                // persistent blocks, 1 per CU
#define TPB 16                  // tiles per block = NTOT/BMT/NBLK
#define THREADS 512
#define PCOLS 218               // 217 numerator cols + denom

typedef __attribute__((ext_vector_type(8))) short bf16x8;
typedef __attribute__((ext_vector_type(4))) float f32x4;

// RNE f32->bf16 bit-trick (compiler-schedulable; NOT inline-asm cvt_pk — m240)
static __device__ __forceinline__ unsigned short f2bf(float f) {
  union { float f; unsigned int u; } v;
  v.f = f;
  unsigned int u = v.u;
  return (unsigned short)((u + 0x7FFFu + ((u >> 16) & 1u)) >> 16);
}

static __device__ __forceinline__ bf16x8 pack8(float4 a, float4 b) {
  bf16x8 r;
  r[0] = (short)f2bf(a.x); r[1] = (short)f2bf(a.y);
  r[2] = (short)f2bf(a.z); r[3] = (short)f2bf(a.w);
  r[4] = (short)f2bf(b.x); r[5] = (short)f2bf(b.y);
  r[6] = (short)f2bf(b.z); r[7] = (short)f2bf(b.w);
  return r;
}

// raw barrier: drain own LDS ops, sync — global loads stay in flight
#define BAR()                                            \
  {                                                      \
    asm volatile("s_waitcnt lgkmcnt(0)" ::: "memory");   \
    __builtin_amdgcn_s_barrier();                        \
  }

__global__ __launch_bounds__(THREADS, 2) void fused_kernel(
    const float* __restrict__ pe, const float* __restrict__ b1g,
    const float* __restrict__ b2g, const float* __restrict__ W1,
    const float* __restrict__ W2, float* __restrict__ part) {
  // afrag: CVT-writer-uniform layout (r2-verified). hbuf: writer-contiguous
  // swizzle (r5; conflict-free on both sides).
  __shared__ __align__(16) unsigned short afrag[2 * BMT * H];  // 2 x 32 KB, fragment-linear bf16
  __shared__ __align__(16) unsigned short hbuf[BMT * H];       // 32 KB, writer-contiguous bf16
  __shared__ __align__(16) float e_lds[BMT];

  const int tid = threadIdx.x;
  const int blk = blockIdx.x;
  const int w = tid >> 6;
  const int l = tid & 63;
  const int l15 = l & 15;
  const int hi = l >> 4;
  const size_t row0 = (size_t)blk * (BMT * TPB);   // 1024 rows/block, batch = blk>>2

  // ---- persistent B fragments, gathered DIRECTLY from f32 W1/W2 (prep kernel
  // merged away: saves one launch + gap + the w1t/w2t HBM round-trip).
  // b1r[cc][s][e] = bf16(W1[k][col1]), k = s*32+hi*8+e  (== old w1t layout)
  // Weights are L2/L3-resident after first touch (480 KB/block aggregate).
  const int nct2 = (w < 6) ? 2 : 1;
  bf16x8 b1r[2][8], b2r[2][8];
  int jcol[2];
  float bc1[2], bj2[2];
  #pragma unroll
  for (int cc = 0; cc < 2; ++cc) {
    const int col1 = (2 * w + cc) * 16 + l15;
    const int ct2 = (w < 6) ? (2 * w + cc) : (6 + w);  // w6->12, w7->13
    const int col2 = ct2 * 16 + l15;
    jcol[cc] = col2;
    bc1[cc] = b1g[col1];
    bj2[cc] = (col2 < OUTD) ? b2g[col2] : 0.f;
    #pragma unroll
    for (int s = 0; s < 8; ++s) {
      #pragma unroll
      for (int e = 0; e < 8; ++e) {
        const int k = s * 32 + hi * 8 + e;
        b1r[cc][s][e] = (short)f2bf(W1[k * H + col1]);
        unsigned short v2 = 0;
        if (col2 < OUTD) v2 = f2bf(W2[k * OUTD + col2]);  // exec-masked: no OOB read
        b2r[cc][s][e] = (short)v2;
      }
    }
  }
  const float b2c0 = b2g[0];

  // ---- reg-staged prefetch: tile T's pe rows -> ld[4][2] (32 VGPRs in flight) ----
  float4 ld[4][2];
#define ISSUE(T)                                                             \
  {                                                                          \
    const float* g = pe + (row0 + (size_t)(T) * BMT) * H;                    \
    _Pragma("unroll") for (int j2 = 0; j2 < 4; ++j2) {                       \
      const int idx = tid + j2 * THREADS;                                    \
      const float* a = g + (idx >> 5) * H + (idx & 31) * 8;                  \
      ld[j2][0] = *(const float4*)a;                                         \
      ld[j2][1] = *(const float4*)(a + 4);                                   \
    }                                                                        \
  }

  // ---- convert: ld regs f32 -> afrag[buf] bf16, fragment-linear layout ----
#define CVT(buf)                                                             \
  {                                                                          \
    unsigned short* dst = afrag + (buf) * (BMT * H);                         \
    _Pragma("unroll") for (int j2 = 0; j2 < 4; ++j2) {                       \
      const int idx = tid + j2 * THREADS;                                    \
      const int row = idx >> 5, k8 = idx & 31;                               \
      const int ff = row >> 4, ss = k8 >> 2, hh = k8 & 3, ll = row & 15;     \
      const int p = (ll * 4 + hh + ss) & 63;                                 \
      *(bf16x8*)&dst[(ff * 8 + ss) * 512 + p * 8] = pack8(ld[j2][0], ld[j2][1]); \
    }                                                                        \
  }

  // ---- prologue: stage tile 0, put tile 1 in flight ----
  ISSUE(0);
  __builtin_amdgcn_sched_barrier(0);
  CVT(0);
  BAR();
  ISSUE(1);

  float psum[2] = {0.f, 0.f};
  float dsum = 0.f;
  int cur = 0;

  for (int t = 0; t < TPB; ++t) {
    const unsigned short* A = afrag + cur * (BMT * H);

    // ---- GEMM1: 4 f-frags x 2 coltiles, k=256, reads afrag[cur] ----
    f32x4 acc[4][2];
    #pragma unroll
    for (int f = 0; f < 4; ++f) { acc[f][0] = (f32x4)0.f; acc[f][1] = (f32x4)0.f; }
    #pragma unroll
    for (int s = 0; s < 8; ++s) {
      const int p = (l15 * 4 + hi + s) & 63;
      bf16x8 af[4];
      #pragma unroll
      for (int f = 0; f < 4; ++f)
        af[f] = *(const bf16x8*)&A[(f * 8 + s) * 512 + p * 8];
      #pragma unroll
      for (int f = 0; f < 4; ++f) {
        acc[f][0] = __builtin_amdgcn_mfma_f32_16x16x32_bf16(af[f], b1r[0][s], acc[f][0], 0, 0, 0);
        acc[f][1] = __builtin_amdgcn_mfma_f32_16x16x32_bf16(af[f], b1r[1][s], acc[f][1], 0, 0, 0);
      }
    }

    // ---- h = leaky(acc + b1) -> hbuf, writer-contiguous layout (r5) ----
    #pragma unroll
    for (int cc = 0; cc < 2; ++cc) {
      const int col = (2 * w + cc) * 16 + l15;        // GEMM1 output col
      const int s2 = col >> 5;                        // = w
      const int e8 = (l15 >> 3) & 1;                  // hb&1
      const int j2 = col & 7;
      #pragma unroll
      for (int f = 0; f < 4; ++f) {
        #pragma unroll
        for (int r = 0; r < 4; ++r) {
          float hv = acc[f][cc][r] + bc1[cc];
          hv = fmaxf(hv, 0.02f * hv);                 // leaky relu
          const int p2 = e8 | (hi << 1) | (cc << 3) | (r << 4);
          hbuf[(f * 8 + s2) * 512 + p2 * 8 + j2] = f2bf(hv);
        }
      }
    }
    BAR();  // BAR1: h visible to all waves

    // ---- GEMM2: ae = h @ W2, reads hbuf (reader p: 64 distinct rows) ----
    const int ph = (hi & 1) | ((l15 >> 2) << 1) | ((hi >> 1) << 3) | ((l15 & 3) << 4);
    #pragma unroll
    for (int f = 0; f < 4; ++f) { acc[f][0] = (f32x4)0.f; acc[f][1] = (f32x4)0.f; }
    #pragma unroll
    for (int s = 0; s < 8; ++s) {
      bf16x8 af[4];
      #pragma unroll
      for (int f = 0; f < 4; ++f)
        af[f] = *(const bf16x8*)&hbuf[(f * 8 + s) * 512 + ph * 8];
      #pragma unroll
      for (int f = 0; f < 4; ++f) {
        acc[f][0] = __builtin_amdgcn_mfma_f32_16x16x32_bf16(af[f], b2r[0][s], acc[f][0], 0, 0, 0);
      }
      if (nct2 == 2) {
        #pragma unroll
        for (int f = 0; f < 4; ++f) {
          acc[f][1] = __builtin_amdgcn_mfma_f32_16x16x32_bf16(af[f], b2r[1][s], acc[f][1], 0, 0, 0);
        }
      }
    }

    // ---- e = exp(logit): col 0 lives in wave 0, lanes l15==0 ----
    if (w == 0 && l15 == 0) {
      #pragma unroll
      for (int f = 0; f < 4; ++f) {
        #pragma unroll
        for (int r = 0; r < 4; ++r) {
          e_lds[f * 16 + hi * 4 + r] = __expf(acc[f][0][r] + b2c0);
        }
      }
    }

    // ---- convert next tile into afrag[cur^1]; then IMMEDIATELY issue tile
    // t+2 (ld regs dead here; in-order issue makes the WAR safe). Issuing
    // before BAR2 (which doesn't drain vmcnt) extends the prefetch window
    // from ~0.6 tile to a full tile+ — delivery (≈6.2k cyc) now has 2x margin,
    // removing the marginal vmcnt stalls at next tile's CVT.
    if (t + 1 < TPB) {
      __builtin_amdgcn_sched_barrier(0);
      CVT(cur ^ 1);
      __builtin_amdgcn_sched_barrier(0);
      if (t + 2 < TPB) ISSUE(t + 2);
      __builtin_amdgcn_sched_barrier(0);
    }
    BAR();  // BAR2: e_lds + converted afrag visible; all hbuf reads done

    // ---- accumulate softmax-weighted partials in registers ----
    #pragma unroll
    for (int f = 0; f < 4; ++f) {
      const f32x4 ev = *(const f32x4*)&e_lds[f * 16 + hi * 4];
      #pragma unroll
      for (int r = 0; r < 4; ++r) {
        psum[0] += ev[r] * (acc[f][0][r] + bj2[0]);
        if (nct2 == 2) psum[1] += ev[r] * (acc[f][1][r] + bj2[1]);
      }
    }
    if (w == 1) dsum += e_lds[l];

    cur ^= 1;
  }

  // ---- store per-block partials (no atomics) ----
  #pragma unroll
  for (int cc = 0; cc < 2; ++cc) {
    psum[cc] += __shfl_xor(psum[cc], 16);
    psum[cc] += __shfl_xor(psum[cc], 32);
  }
  if (hi == 0) {
    for (int cc = 0; cc < nct2; ++cc) {
      int j = jcol[cc];
      if (j >= 1 && j < OUTD) part[blk * PCOLS + (j - 1)] = psum[cc];
    }
  }
  if (w == 1) {
    #pragma unroll
    for (int m = 1; m < 64; m <<= 1) dsum += __shfl_xor(dsum, m);
    if (l == 0) part[blk * PCOLS + 217] = dsum;
  }
#undef ISSUE
#undef CVT
}

__global__ __launch_bounds__(256) void finalize_kernel(
    const float* __restrict__ part, float* __restrict__ out) {
  int b = blockIdx.x;
  int t = threadIdx.x;
  if (t < 217) {
    float s = 0.f, d = 0.f;
    #pragma unroll
    for (int i = 0; i < NBLK / NBATCH; ++i) {   // 4 blocks per batch
      const float* p = part + (size_t)(b * (NBLK / NBATCH) + i) * PCOLS;
      s += p[t];
      d += p[217];
    }
    float v = s / d;
    if (t < 216) out[b * 216 + t] = v;        // xr: (64, 72, 3) flat
    else out[NBATCH * 216 + b] = v;           // xo: (64,)
  }
}

extern "C" void kernel_launch(void* const* d_in, const int* in_sizes, int n_in,
                              void* d_out, int out_size, void* d_ws, size_t ws_size,
                              hipStream_t stream) {
  (void)in_sizes; (void)n_in; (void)out_size; (void)ws_size;
  const float* pe = (const float*)d_in[0];
  const float* W1 = (const float*)d_in[1];
  const float* b1 = (const float*)d_in[2];
  const float* W2 = (const float*)d_in[3];
  const float* b2 = (const float*)d_in[4];

  float* part = (float*)d_ws;                           // 256*218*4 B

  fused_kernel<<<NBLK, THREADS, 0, stream>>>(pe, b1, b2, W1, W2, part);
  finalize_kernel<<<NBATCH, 256, 0, stream>>>(part, (float*)d_out);
}